// Round 4
// baseline (176.103 us; speedup 1.0000x reference)
//
#include <hip/hip_runtime.h>

using half8 = __attribute__((ext_vector_type(8))) _Float16;
using f32x4 = __attribute__((ext_vector_type(4))) float;

#define Lc 4096
#define Ec 64
#define Mc 64
#define BHc 128

// 2*pi/4096
#define TWO_PI_OVER_L 1.5339807878856412e-3f

// ---------------------------------------------------------------------------
// Twiddle tables, both coalesced:
//   Tt[m2][l]  f16, m2 in [0,128): rows 0..63 = cos(th), rows 64..127 = -sin(th)
//   UL[l][m2]  f16: cols 0..63 = cos(th), cols 64..127 = +sin(th)
// th = 2*pi*k_m*l/L
// ---------------------------------------------------------------------------
__global__ __launch_bounds__(256) void twid_k(const int* __restrict__ idx,
                                              _Float16* __restrict__ Tt,
                                              _Float16* __restrict__ UL) {
    int id = blockIdx.x * 256 + threadIdx.x;   // 0 .. 524287
    {   // UL pass: l = id>>7, m2 = id&127  (coalesced in m2)
        int l = id >> 7, m2 = id & 127, m = m2 & 63;
        int k = idx[m];
        int ph = (k * l) & (Lc - 1);
        float s, c;
        sincosf((float)ph * TWO_PI_OVER_L, &s, &c);
        UL[id] = (_Float16)((m2 >= 64) ? s : c);
    }
    {   // Tt pass: m2 = id>>12, l = id&4095  (coalesced in l)
        int m2 = id >> 12, l = id & 4095, m = m2 & 63;
        int k = idx[m];
        int ph = (k * l) & (Lc - 1);
        float s, c;
        sincosf((float)ph * TWO_PI_OVER_L, &s, &c);
        Tt[id] = (_Float16)((m2 >= 64) ? -s : c);
    }
}

// ---------------------------------------------------------------------------
// Forward: selP[ch][bh][m2=128][e=64] = sum_{l in chunk} Tt[m2][l] * x[bh][l][e]
// grid (BHc, NCH), 256 thr (4 waves). Wave w owns e-columns [16w, 16w+16),
// all 128 m2 rows. NO LDS, NO barriers: B-fragments (x) are built from 8
// coalesced scalar dword loads per lane (lanes 0..15 = one 64B line) + reg
// f32->f16 convert; A-fragments (Tt) are contiguous half8 from L2-resident Tt.
// MFMA mapping (16x16x32): A row=lane&15, k=(lane>>4)*8+i; B col=lane&15;
// D col=lane&15, row=(lane>>4)*4+reg.
// ---------------------------------------------------------------------------
template<int NCH>
__global__ __launch_bounds__(256) void fwd_k(const float* __restrict__ x,
                                             const _Float16* __restrict__ Tt,
                                             float* __restrict__ selP) {
    constexpr int CH = Lc / NCH;
    constexpr int NS = CH / 32;                // k-steps of 32
    int bh = blockIdx.x, ch = blockIdx.y;
    int tid = threadIdx.x, lane = tid & 63, w = tid >> 6;
    int lo16 = lane & 15, kg = lane >> 4;

    const float* xp = x + ((size_t)bh * Lc + (size_t)ch * CH + kg * 8) * Ec
                        + w * 16 + lo16;               // + l*Ec walks l
    const _Float16* tp = Tt + (size_t)lo16 * Lc + ch * CH + kg * 8;

    f32x4 acc[8] = {};
    for (int s = 0; s < NS; ++s) {
        const float* gx = xp + (size_t)s * 32 * Ec;
        float f[8];
        #pragma unroll
        for (int i = 0; i < 8; ++i) f[i] = gx[(size_t)i * Ec];
        half8 B;
        #pragma unroll
        for (int i = 0; i < 8; ++i) B[i] = (_Float16)f[i];
        #pragma unroll
        for (int a = 0; a < 8; ++a) {
            half8 A = *(const half8*)(tp + (size_t)a * 16 * Lc + s * 32);
            acc[a] = __builtin_amdgcn_mfma_f32_16x16x32_f16(A, B, acc[a], 0, 0, 0);
        }
    }
    float* op = selP + (size_t)(ch * BHc + bh) * (128 * Ec);
    #pragma unroll
    for (int a = 0; a < 8; ++a)
        #pragma unroll
        for (int r = 0; r < 4; ++r) {
            int m2 = a * 16 + kg * 4 + r;
            op[m2 * Ec + w * 16 + lo16] = acc[a][r];
        }
}

// ---------------------------------------------------------------------------
// Mix: reduce K-partials, apply complex weight einsum, fold irfft scale.
// Vt[bh][o=64][m2=128] f16: cols 0..63 = s*Re(out_sel), 64..127 = -s*Im(out_sel)
// grid (BHc, 2) o-halves, 256 thr. Thread owns 4 o x 2 m.
// ---------------------------------------------------------------------------
__global__ __launch_bounds__(256) void mix_k(const float* __restrict__ selP,
                                             const float* __restrict__ wgt,
                                             const int* __restrict__ idx,
                                             _Float16* __restrict__ Vt, int nch) {
    __shared__ float sel_s[128 * 65];          // [m2][65] padded, 33.3KB
    int bh = blockIdx.x, oh = blockIdx.y;
    int tid = threadIdx.x;
    #pragma unroll
    for (int i = 0; i < 8; ++i) {
        int f4 = i * 256 + tid;                // 2048 float4 = 8192 floats
        float4 a = make_float4(0.f, 0.f, 0.f, 0.f);
        for (int chn = 0; chn < nch; ++chn) {
            float4 v = *((const float4*)(selP + (size_t)(chn * BHc + bh) * 8192) + f4);
            a.x += v.x; a.y += v.y; a.z += v.z; a.w += v.w;
        }
        int m2 = f4 >> 4, e4 = (f4 & 15) * 4;
        float* dst = &sel_s[m2 * 65 + e4];
        dst[0] = a.x; dst[1] = a.y; dst[2] = a.z; dst[3] = a.w;
    }
    __syncthreads();
    int og = tid & 7, mg = tid >> 3;
    int o0 = oh * 32 + og * 4;
    int m0 = mg * 2;
    float rR[4][2] = {{0}}, rI[4][2] = {{0}};
    for (int e = 0; e < Ec; ++e) {
        float sr0 = sel_s[m0 * 65 + e];
        float sr1 = sel_s[(m0 + 1) * 65 + e];
        float si0 = sel_s[(64 + m0) * 65 + e];
        float si1 = sel_s[(64 + m0 + 1) * 65 + e];
        #pragma unroll
        for (int i = 0; i < 4; ++i) {
            const float4* wp = (const float4*)&wgt[(((size_t)e * Ec + (o0 + i)) * Mc + m0) * 2];
            float4 wv = *wp;   // wR[m0], wI[m0], wR[m0+1], wI[m0+1]
            rR[i][0] += sr0 * wv.x - si0 * wv.y;
            rI[i][0] += sr0 * wv.y + si0 * wv.x;
            rR[i][1] += sr1 * wv.z - si1 * wv.w;
            rI[i][1] += sr1 * wv.w + si1 * wv.z;
        }
    }
    float s0 = (idx[m0] == 0 ? 1.0f : 2.0f) / (float)Lc;
    float s1 = (idx[m0 + 1] == 0 ? 1.0f : 2.0f) / (float)Lc;
    #pragma unroll
    for (int i = 0; i < 4; ++i) {
        _Float16* vp = Vt + ((size_t)bh * 64 + o0 + i) * 128;
        unsigned short r0 = __builtin_bit_cast(unsigned short, (_Float16)(rR[i][0] * s0));
        unsigned short r1 = __builtin_bit_cast(unsigned short, (_Float16)(rR[i][1] * s1));
        unsigned short i0 = __builtin_bit_cast(unsigned short, (_Float16)(-rI[i][0] * s0));
        unsigned short i1 = __builtin_bit_cast(unsigned short, (_Float16)(-rI[i][1] * s1));
        *(unsigned int*)&vp[m0]      = r0 | ((unsigned int)r1 << 16);
        *(unsigned int*)&vp[64 + m0] = i0 | ((unsigned int)i1 << 16);
    }
}

// ---------------------------------------------------------------------------
// Inverse: out[bh][l][o] = sum_{m2} UL[l][m2] * V[m2][o]
// grid (BHc, 16), 256 thr. Wave w owns l rows [64w, 64w+64) of a 256-l block.
// NO LDS, NO barriers: Vt (16KB/bh) is L2-resident -> B fragments straight
// from global (contiguous half8); A fragments contiguous half8 from UL.
// ---------------------------------------------------------------------------
__global__ __launch_bounds__(256) void inv_k(const _Float16* __restrict__ UL,
                                             const _Float16* __restrict__ Vt,
                                             float* __restrict__ out) {
    int bh = blockIdx.x, lb = blockIdx.y;
    int tid = threadIdx.x, lane = tid & 63, w = tid >> 6;
    int lo16 = lane & 15, kg = lane >> 4;
    int lt0 = lb * 256 + w * 64;
    const _Float16* up = UL + (size_t)(lt0 + lo16) * 128 + kg * 8;
    const _Float16* vp = Vt + (size_t)bh * 8192 + (size_t)lo16 * 128 + kg * 8;
    f32x4 acc[4][4] = {};
    #pragma unroll
    for (int ks = 0; ks < 4; ++ks) {
        half8 Af[4], Bf[4];
        #pragma unroll
        for (int a = 0; a < 4; ++a)
            Af[a] = *(const half8*)(up + (size_t)a * 16 * 128 + ks * 32);
        #pragma unroll
        for (int j = 0; j < 4; ++j)
            Bf[j] = *(const half8*)(vp + (size_t)j * 16 * 128 + ks * 32);
        #pragma unroll
        for (int j = 0; j < 4; ++j)
            #pragma unroll
            for (int a = 0; a < 4; ++a)
                acc[a][j] = __builtin_amdgcn_mfma_f32_16x16x32_f16(Af[a], Bf[j], acc[a][j], 0, 0, 0);
    }
    float* op = out + ((size_t)bh * Lc + lt0) * Ec;
    #pragma unroll
    for (int a = 0; a < 4; ++a)
        #pragma unroll
        for (int j = 0; j < 4; ++j)
            #pragma unroll
            for (int r = 0; r < 4; ++r) {
                int ll = a * 16 + kg * 4 + r;
                int o  = 16 * j + lo16;
                op[ll * Ec + o] = acc[a][j][r];
            }
}

// ---------------------------------------------------------------------------
extern "C" void kernel_launch(void* const* d_in, const int* in_sizes, int n_in,
                              void* d_out, int out_size, void* d_ws, size_t ws_size,
                              hipStream_t stream) {
    const float* x   = (const float*)d_in[0];
    const float* wgt = (const float*)d_in[1];
    const int*   idx = (const int*)d_in[2];
    float* out = (float*)d_out;

    // workspace layout: selP (nch*4MB) | Tt (1MB) | UL (1MB) | Vt (2MB)
    size_t need8 = (size_t)8 * BHc * 8192 * 4 + (2ull * 128 * Lc + (size_t)BHc * 8192) * 2;
    int nch = (ws_size >= need8) ? 8 : 4;

    char* ws = (char*)d_ws;
    float*    selP = (float*)ws;
    _Float16* Tt   = (_Float16*)(ws + (size_t)nch * BHc * 8192 * 4);
    _Float16* UL   = Tt + (size_t)128 * Lc;
    _Float16* Vt   = UL + (size_t)Lc * 128;

    twid_k<<<2048, 256, 0, stream>>>(idx, Tt, UL);
    if (nch == 8)
        fwd_k<8><<<dim3(BHc, 8), 256, 0, stream>>>(x, Tt, selP);
    else
        fwd_k<4><<<dim3(BHc, 4), 256, 0, stream>>>(x, Tt, selP);
    mix_k<<<dim3(BHc, 2), 256, 0, stream>>>(selP, wgt, idx, Vt, nch);
    inv_k<<<dim3(BHc, 16), 256, 0, stream>>>(UL, Vt, out);
}